// Round 4
// baseline (542.515 us; speedup 1.0000x reference)
//
#include <hip/hip_runtime.h>
#include <stdint.h>

#define B_  16384
#define IN_ 512
#define H_  1024
#define KC_ 1536   // IN_ + H_

typedef unsigned short u16;
typedef __attribute__((ext_vector_type(4))) float f32x4;
typedef __attribute__((ext_vector_type(8))) short s16x8;

// ---------- helpers ----------

__device__ __forceinline__ u16 f2bf(float f) {
  union { float f; uint32_t u; } un; un.f = f;
  uint32_t u = un.u;
  uint32_t r = (u + 0x7FFFu + ((u >> 16) & 1u)) >> 16;   // RNE
  return (u16)r;
}

__device__ __forceinline__ float fast_sigmoid(float x) {
  return 1.f / (1.f + __expf(-x));
}
__device__ __forceinline__ float fast_tanh(float x) {
  return 1.f - 2.f / (1.f + __expf(2.f * x));
}

__device__ __forceinline__ void mfma_bf16(f32x4& d, s16x8 a, s16x8 b) {
  asm volatile("v_mfma_f32_16x16x32_bf16 %0, %1, %2, %0" : "+v"(d) : "v"(a), "v"(b));
}

__device__ __forceinline__ void async_copy16(void* lds, const void* g) {
  __builtin_amdgcn_global_load_lds(
      (const __attribute__((address_space(1))) void*)g,
      (__attribute__((address_space(3))) void*)lds, 16, 0, 0);
}

// ---------- K0: f32 -> bf16 conversion / packing ----------
__global__ __launch_bounds__(256)
void k0_convert(const float* __restrict__ x, const float* __restrict__ hprev,
                const float* __restrict__ Wi, const float* __restrict__ Wf,
                const float* __restrict__ Wo, const float* __restrict__ Wg,
                const float* __restrict__ Wht, const float* __restrict__ Whg,
                u16* __restrict__ comb, u16* __restrict__ wcat,
                u16* __restrict__ wht2)
{
  const int NC_COMB = (B_ * KC_) / 4;          // 6291456
  const int NC_WCAT = (4 * H_ * KC_) / 4;      // 1572864
  const int NC_WHT  = (2 * H_ * IN_) / 4;      // 262144
  const int TOTAL = NC_COMB + NC_WCAT + NC_WHT;
  const int stride = gridDim.x * blockDim.x;

  for (int idx = blockIdx.x * blockDim.x + threadIdx.x; idx < TOTAL; idx += stride) {
    const float* src;
    u16* dst;
    if (idx < NC_COMB) {
      int row = idx / 384, cq = idx % 384;
      src = (cq < 128) ? (x + (size_t)row * IN_ + cq * 4)
                       : (hprev + (size_t)row * H_ + (cq - 128) * 4);
      dst = comb + (size_t)idx * 4;
    } else if (idx < NC_COMB + NC_WCAT) {
      int j = idx - NC_COMB;
      int g = j / 393216;
      int rem = j % 393216;
      const float* W = (g == 0) ? Wi : (g == 1) ? Wf : (g == 2) ? Wo : Wg;
      src = W + (size_t)rem * 4;
      dst = wcat + (size_t)j * 4;
    } else {
      int j = idx - NC_COMB - NC_WCAT;
      int m = j / 131072;
      int rem = j % 131072;
      src = (m ? Whg : Wht) + (size_t)rem * 4;
      dst = wht2 + (size_t)j * 4;
    }
    float4 v = *(const float4*)src;
    uint32_t p0 = (uint32_t)f2bf(v.x) | ((uint32_t)f2bf(v.y) << 16);
    uint32_t p1 = (uint32_t)f2bf(v.z) | ((uint32_t)f2bf(v.w) << 16);
    *(uint2*)dst = make_uint2(p0, p1);
  }
}

// ---------- K1: 256x256-tile 8-phase gate GEMM + LSTM pointwise ----------
// BM=256, BN=256 eff (4 gates x 64 h), BK=64. 8 waves (2M x 4N), per-wave
// strip-reordered 128x64: wave wm owns rows {wm*64..+64} U {128+wm*64..+64}
// so A-half0 dies after phase 2, A-half1 after phase 4 (restageable mid-iter).
// Iteration = 2 K-tiles (even->buf0 ph1-4, odd->buf1 ph5-8). Stage 1
// half-tile/phase, 3 half-tiles in flight, vmcnt(6) at ph4/ph8 ONLY (T3+T4);
// stage->consume distance 5-7 phases (covers ~900cyc HBM latency).
__global__ __launch_bounds__(512, 2)
void k1_gates8ph(const u16* __restrict__ comb, const u16* __restrict__ wcat,
                 const float* __restrict__ bi, const float* __restrict__ bf_,
                 const float* __restrict__ bo, const float* __restrict__ bg,
                 const float* __restrict__ c_prev,
                 float* __restrict__ c_out, float* __restrict__ h_pre)
{
  __shared__ __attribute__((aligned(128))) char lds[131072];

  const int tid = threadIdx.x;
  const int w = tid >> 6, lane = tid & 63;
  const int lrow = lane & 15, lkg = lane >> 4;
  const int wm = w >> 2, wn = w & 3;

  // XCD-aware bijective swizzle (nwg=1024, 1024%8==0)
  int bid = blockIdx.y * gridDim.x + blockIdx.x;
  int swz = (bid & 7) * 128 + (bid >> 3);
  const int bx = swz & 15, by = swz >> 4;
  const int m0 = by * 256, n0h = bx * 64;

  // ---- staging source pointers & LDS dest offsets (half h, load t) ----
  // global_load_lds: LDS dest base is wave-uniform (HW adds lane*16);
  // global source is per-lane, inverse-chunk-swizzled (rule 21).
  const u16* pA[2][2]; const u16* pB[2][2];
  int ldsA[2][2], ldsB[2][2];
#pragma unroll
  for (int h = 0; h < 2; ++h)
#pragma unroll
    for (int t = 0; t < 2; ++t) {
      int i = w * 128 + t * 64 + lane;     // 0..1023 chunk index in half-tile
      int rh = i >> 3, c = i & 7;
      int cs = c ^ (rh & 7);               // inverse-swizzled source chunk
      int rt = h * 128 + rh;               // row in 256-row tile
      pA[h][t] = comb + (size_t)(m0 + rt) * KC_ + cs * 8;
      int g = (rt >> 4) & 3, hc = n0h + ((rt >> 6) << 4) + (rt & 15);
      pB[h][t] = wcat + ((size_t)(g * H_ + hc)) * KC_ + cs * 8;
      ldsA[h][t] = h * 16384 + (w * 128 + t * 64) * 16;            // wave-uniform
      ldsB[h][t] = 32768 + h * 16384 + (w * 128 + t * 64) * 16;
    }

  // ---- ds_read offsets (strip-reordered frags) ----
  // frag f: tile row = (f>>2)*128 + wm*64 + (f&3)*16 + lrow
  int aoff[8], boff[4];
#pragma unroll
  for (int f = 0; f < 8; ++f)
    aoff[f] = ((f >> 2) * 128 + wm * 64 + (f & 3) * 16 + lrow) * 128;
#pragma unroll
  for (int fc = 0; fc < 4; ++fc)
    boff[fc] = 32768 + (wn * 64 + fc * 16 + lrow) * 128;
  const int kx0 = ((lkg) ^ (lrow & 7)) << 4;
  const int kx1 = ((4 + lkg) ^ (lrow & 7)) << 4;

  f32x4 acc[8][4];
#pragma unroll
  for (int i = 0; i < 8; ++i)
#pragma unroll
    for (int j = 0; j < 4; ++j) acc[i][j] = (f32x4){0.f, 0.f, 0.f, 0.f};

  char* const buf0 = lds;
  char* const buf1 = lds + 65536;

#define SA(bufp, h, T) { async_copy16((bufp) + ldsA[h][0], pA[h][0] + (T) * 64); \
                         async_copy16((bufp) + ldsA[h][1], pA[h][1] + (T) * 64); }
#define SB(bufp, h, T) { async_copy16((bufp) + ldsB[h][0], pB[h][0] + (T) * 64); \
                         async_copy16((bufp) + ldsB[h][1], pB[h][1] + (T) * 64); }

  // ---- prologue: tile0 (full) -> buf0; tile1 {B0,B1,A0} -> buf1 ----
  SB(buf0, 0, 0) SB(buf0, 1, 0) SA(buf0, 0, 0) SA(buf0, 1, 0)
  SB(buf1, 0, 1) SB(buf1, 1, 1) SA(buf1, 0, 1)
  asm volatile("s_waitcnt vmcnt(6)" ::: "memory");
  __builtin_amdgcn_sched_barrier(0);
  __builtin_amdgcn_s_barrier();

  s16x8 bfr[4][2];

#define PHASE(Q, bufc, STAGE, TAILWAIT)                                        \
  {                                                                            \
    s16x8 a0k0 = *(const s16x8*)((bufc) + aoff[2*(Q)]     + kx0);              \
    s16x8 a1k0 = *(const s16x8*)((bufc) + aoff[2*(Q) + 1] + kx0);              \
    s16x8 a0k1 = *(const s16x8*)((bufc) + aoff[2*(Q)]     + kx1);              \
    s16x8 a1k1 = *(const s16x8*)((bufc) + aoff[2*(Q) + 1] + kx1);              \
    if ((Q) == 0) {                                                            \
      _Pragma("unroll")                                                        \
      for (int fc = 0; fc < 4; ++fc) {                                         \
        bfr[fc][0] = *(const s16x8*)((bufc) + boff[fc] + kx0);                 \
        bfr[fc][1] = *(const s16x8*)((bufc) + boff[fc] + kx1);                 \
      }                                                                        \
    }                                                                          \
    STAGE;                                                                     \
    __builtin_amdgcn_sched_barrier(0);                                         \
    __builtin_amdgcn_s_barrier();                                              \
    asm volatile("s_waitcnt lgkmcnt(0)" ::: "memory");                         \
    __builtin_amdgcn_sched_barrier(0);                                         \
    __builtin_amdgcn_s_setprio(1);                                             \
    _Pragma("unroll")                                                          \
    for (int fc = 0; fc < 4; ++fc) {                                           \
      mfma_bf16(acc[2*(Q)][fc],     a0k0, bfr[fc][0]);                         \
      mfma_bf16(acc[2*(Q) + 1][fc], a1k0, bfr[fc][0]);                         \
    }                                                                          \
    _Pragma("unroll")                                                          \
    for (int fc = 0; fc < 4; ++fc) {                                           \
      mfma_bf16(acc[2*(Q)][fc],     a0k1, bfr[fc][1]);                         \
      mfma_bf16(acc[2*(Q) + 1][fc], a1k1, bfr[fc][1]);                         \
    }                                                                          \
    __builtin_amdgcn_s_setprio(0);                                             \
    TAILWAIT;                                                                  \
    __builtin_amdgcn_sched_barrier(0);                                         \
    __builtin_amdgcn_s_barrier();                                              \
  }

  // ---- main loop: 12 iterations x 2 K-tiles ----
  for (int i = 0; i < 12; ++i) {
    const int t2 = 2 * i + 2, t3 = 2 * i + 3;
    const bool more = (i < 11);
    // tiles 2i (buf0) phases 1-4
    PHASE(0, buf0, { SA(buf1, 1, 2 * i + 1) }, {})
    PHASE(1, buf0, { if (more) SB(buf0, 0, t2) }, {})
    PHASE(2, buf0, { if (more) SB(buf0, 1, t2) }, {})
    PHASE(3, buf0, { if (more) SA(buf0, 0, t2) },
          { if (more) asm volatile("s_waitcnt vmcnt(6)" ::: "memory");
            else      asm volatile("s_waitcnt vmcnt(0)" ::: "memory"); })
    // tile 2i+1 (buf1) phases 5-8
    PHASE(0, buf1, { if (more) SA(buf0, 1, t2) }, {})
    PHASE(1, buf1, { if (more) SB(buf1, 0, t3) }, {})
    PHASE(2, buf1, { if (more) SB(buf1, 1, t3) }, {})
    PHASE(3, buf1, { if (more) SA(buf1, 0, t3) },
          { asm volatile("s_waitcnt vmcnt(6)" ::: "memory"); })
  }
#undef PHASE
#undef SA
#undef SB

  // ---- epilogue: i,f,o,g -> c, h_pre (strip-reordered rows) ----
  const int hcol = n0h + wn * 16 + lrow;
  const float vbi = bi[hcol], vbf = bf_[hcol], vbo = bo[hcol], vbg = bg[hcol];
#pragma unroll
  for (int f = 0; f < 8; ++f) {
    const int row0 = m0 + (f >> 2) * 128 + wm * 64 + (f & 3) * 16 + lkg * 4;
#pragma unroll
    for (int r4 = 0; r4 < 4; ++r4) {
      const size_t off = (size_t)(row0 + r4) * H_ + hcol;
      float iv = fast_sigmoid(acc[f][0][r4] + vbi);
      float fv = fast_sigmoid(acc[f][1][r4] + vbf);
      float ov = fast_sigmoid(acc[f][2][r4] + vbo);
      float gv = fast_tanh(acc[f][3][r4] + vbg);
      float c = fv * c_prev[off] + iv * gv;
      c_out[off] = c;
      h_pre[off] = ov * fast_tanh(c);
    }
  }
}

// ---------- K2a: attention logits + exp, per-block partial sums ----------
__global__ __launch_bounds__(256)
void k2_logits(const float* __restrict__ h_pre, const float* __restrict__ Wa,
               const float* __restrict__ ba, float* __restrict__ e,
               float* __restrict__ partial)
{
  __shared__ float wsum[4];
  const int w = threadIdx.x >> 6, lane = threadIdx.x & 63;
  const int r = blockIdx.x * 4 + w;
  const float4* hp = (const float4*)(h_pre + (size_t)r * H_);
  const float4* wa = (const float4*)Wa;
  float s = 0.f;
#pragma unroll
  for (int j = 0; j < 4; ++j) {
    float4 hv = hp[lane * 4 + j];
    float4 wv = wa[lane * 4 + j];
    s += hv.x * wv.x + hv.y * wv.y + hv.z * wv.z + hv.w * wv.w;
  }
#pragma unroll
  for (int off = 32; off; off >>= 1) s += __shfl_xor(s, off);
  float ev = __expf(s + ba[0]);
  if (lane == 0) { e[r] = ev; wsum[w] = ev; }
  __syncthreads();
  if (threadIdx.x == 0) partial[blockIdx.x] = wsum[0] + wsum[1] + wsum[2] + wsum[3];
}

// ---------- K2b: single-block reduction of 4096 partials ----------
__global__ __launch_bounds__(256)
void k2_reduce(const float* __restrict__ partial, float* __restrict__ sum_slot)
{
  __shared__ float ws4[4];
  float s = 0.f;
  for (int i = threadIdx.x; i < 4096; i += 256) s += partial[i];
#pragma unroll
  for (int off = 32; off; off >>= 1) s += __shfl_xor(s, off);
  if ((threadIdx.x & 63) == 0) ws4[threadIdx.x >> 6] = s;
  __syncthreads();
  if (threadIdx.x == 0) sum_slot[0] = ws4[0] + ws4[1] + ws4[2] + ws4[3];
}

// ---------- K3: highway GEMM + attention scale + merge (128^2 2-phase) ----------
__global__ __launch_bounds__(256, 2)
void k3_highway(const u16* __restrict__ comb, const u16* __restrict__ wht2,
                const float* __restrict__ bht, const float* __restrict__ bhg,
                const float* __restrict__ e, const float* __restrict__ sum_slot,
                float* __restrict__ h_out)   // holds h_pre (f32) on entry
{
  __shared__ __attribute__((aligned(128))) char lds[32768];
  char* lds_a = lds;
  char* lds_b = lds + 16384;

  const int tid = threadIdx.x;
  const int w = tid >> 6, lane = tid & 63;
  const int lrow = lane & 15, lkg = lane >> 4;
  const int wm = w >> 1, wn = w & 1;
  const int m0 = blockIdx.y * 128;
  const int h0 = blockIdx.x * 64;

  const u16* agp[4]; const u16* bgp[4];
  char* alp[4]; char* blp[4];
#pragma unroll
  for (int t = 0; t < 4; ++t) {
    int j = w * 256 + t * 64 + lane;
    int r = j >> 3, q = j & 7;
    int qs = q ^ (r & 7);
    agp[t] = comb + (size_t)(m0 + r) * KC_ + qs * 8;        // x part: cols 0..511
    alp[t] = lds_a + (w * 256 + t * 64) * 16;
    int mat = (r >> 4) & 1, n = ((r >> 5) << 4) + (r & 15);
    bgp[t] = wht2 + ((size_t)(mat * H_ + h0 + n)) * IN_ + qs * 8;
    blp[t] = lds_b + (w * 256 + t * 64) * 16;
  }

  f32x4 acc[4][4];
#pragma unroll
  for (int i = 0; i < 4; ++i)
#pragma unroll
    for (int j = 0; j < 4; ++j) acc[i][j] = (f32x4){0.f, 0.f, 0.f, 0.f};

  const int sw = (lrow & 7) << 4;
  int aoff[4], boff[4];
#pragma unroll
  for (int fm = 0; fm < 4; ++fm) aoff[fm] = (wm * 64 + fm * 16 + lrow) * 128;
#pragma unroll
  for (int fc = 0; fc < 4; ++fc) boff[fc] = (wn * 64 + fc * 16 + lrow) * 128;

  for (int kt = 0; kt < IN_ / 64; ++kt) {
#pragma unroll
    for (int t = 0; t < 4; ++t) {
      async_copy16(alp[t], agp[t] + kt * 64);
      async_copy16(blp[t], bgp[t] + kt * 64);
    }
    __syncthreads();
#pragma unroll
    for (int ks = 0; ks < 2; ++ks) {
      const int koff = (ks * 64 + lkg * 16) ^ sw;
      s16x8 a[4], b[4];
#pragma unroll
      for (int fm = 0; fm < 4; ++fm) a[fm] = *(const s16x8*)(lds_a + aoff[fm] + koff);
#pragma unroll
      for (int fc = 0; fc < 4; ++fc) b[fc] = *(const s16x8*)(lds_b + boff[fc] + koff);
#pragma unroll
      for (int fm = 0; fm < 4; ++fm)
#pragma unroll
        for (int fc = 0; fc < 4; ++fc) mfma_bf16(acc[fm][fc], a[fm], b[fc]);
    }
    __syncthreads();
  }

  const float invs = 1.f / sum_slot[0];
  const int hA = h0 + wn * 32 + lrow;
  const float vbht0 = bht[hA], vbht1 = bht[hA + 16];
  const float vbhg0 = bhg[hA], vbhg1 = bhg[hA + 16];
#pragma unroll
  for (int fm = 0; fm < 4; ++fm) {
    const int row0 = m0 + wm * 64 + fm * 16 + lkg * 4;
#pragma unroll
    for (int r4 = 0; r4 < 4; ++r4) {
      const int row = row0 + r4;
      const float escale = e[row] * invs;
#pragma unroll
      for (int hc = 0; hc < 2; ++hc) {
        const int h = hA + hc * 16;
        const size_t off = (size_t)row * H_ + h;
        float tv = acc[fm][2 * hc][r4] + (hc ? vbht1 : vbht0);
        float gv = fast_sigmoid(acc[fm][2 * hc + 1][r4] + (hc ? vbhg1 : vbhg0));
        float ha = h_out[off] * escale;          // h_pre * attn
        h_out[off] = gv * tv + (1.f - gv) * ha;
      }
    }
  }
}

// ---------- launch ----------
extern "C" void kernel_launch(void* const* d_in, const int* in_sizes, int n_in,
                              void* d_out, int out_size, void* d_ws, size_t ws_size,
                              hipStream_t stream) {
  const float* x      = (const float*)d_in[0];
  const float* h_prev = (const float*)d_in[1];
  const float* c_prev = (const float*)d_in[2];
  const float* Wi  = (const float*)d_in[3];
  const float* bi  = (const float*)d_in[4];
  const float* Wf  = (const float*)d_in[5];
  const float* bf_ = (const float*)d_in[6];
  const float* Wo  = (const float*)d_in[7];
  const float* bo  = (const float*)d_in[8];
  const float* Wg  = (const float*)d_in[9];
  const float* bg  = (const float*)d_in[10];
  const float* Wa  = (const float*)d_in[11];
  const float* ba  = (const float*)d_in[12];
  const float* Wht = (const float*)d_in[13];
  const float* bht = (const float*)d_in[14];
  const float* Whg = (const float*)d_in[15];
  const float* bhg = (const float*)d_in[16];

  char* ws = (char*)d_ws;
  float* sum_slot = (float*)(ws + 0);
  float* e        = (float*)(ws + 256);
  u16* comb = (u16*)(ws + 65792);       // 16384*1536*2 = 50331648 B
  u16* wcat = (u16*)(ws + 50397440);    // 4*1024*1536*2 = 12582912 B
  u16* wht2 = (u16*)(ws + 62980352);    // 2*1024*512*2 = 2097152 B -> end 65077504
  float* partial = (float*)(ws + 65077504);   // 4096 floats -> end 65093888

  float* h_out = (float*)d_out;                      // also h_pre scratch (f32)
  float* c_out = (float*)d_out + (size_t)B_ * H_;

  hipLaunchKernelGGL(k0_convert, dim3(2048), dim3(256), 0, stream,
                     x, h_prev, Wi, Wf, Wo, Wg, Wht, Whg, comb, wcat, wht2);
  hipLaunchKernelGGL(k1_gates8ph, dim3(16, 64), dim3(512), 0, stream,
                     comb, wcat, bi, bf_, bo, bg, c_prev, c_out, h_out);
  hipLaunchKernelGGL(k2_logits, dim3(B_ / 4), dim3(256), 0, stream,
                     h_out, Wa, ba, e, partial);
  hipLaunchKernelGGL(k2_reduce, dim3(1), dim3(256), 0, stream,
                     partial, sum_slot);
  hipLaunchKernelGGL(k3_highway, dim3(H_ / 64, B_ / 128), dim3(256), 0, stream,
                     comb, wht2, bht, bhg, e, sum_slot, h_out);
}

// Round 5
// 535.979 us; speedup vs baseline: 1.0122x; 1.0122x over previous
//
#include <hip/hip_runtime.h>
#include <stdint.h>

#define B_  16384
#define IN_ 512
#define H_  1024
#define KC_ 1536   // IN_ + H_

typedef unsigned short u16;
typedef __attribute__((ext_vector_type(4))) float f32x4;
typedef __attribute__((ext_vector_type(8))) short s16x8;

// ---------- helpers ----------

__device__ __forceinline__ u16 f2bf(float f) {
  union { float f; uint32_t u; } un; un.f = f;
  uint32_t u = un.u;
  uint32_t r = (u + 0x7FFFu + ((u >> 16) & 1u)) >> 16;   // RNE
  return (u16)r;
}

__device__ __forceinline__ float fast_sigmoid(float x) {
  return 1.f / (1.f + __expf(-x));
}
__device__ __forceinline__ float fast_tanh(float x) {
  return 1.f - 2.f / (1.f + __expf(2.f * x));
}

__device__ __forceinline__ void mfma_bf16(f32x4& d, s16x8 a, s16x8 b) {
  asm volatile("v_mfma_f32_16x16x32_bf16 %0, %1, %2, %0" : "+v"(d) : "v"(a), "v"(b));
}

__device__ __forceinline__ void async_copy16(void* lds, const void* g) {
  __builtin_amdgcn_global_load_lds(
      (const __attribute__((address_space(1))) void*)g,
      (__attribute__((address_space(3))) void*)lds, 16, 0, 0);
}

// ---------- K0: f32 -> bf16 conversion / packing ----------
__global__ __launch_bounds__(256)
void k0_convert(const float* __restrict__ x, const float* __restrict__ hprev,
                const float* __restrict__ Wi, const float* __restrict__ Wf,
                const float* __restrict__ Wo, const float* __restrict__ Wg,
                const float* __restrict__ Wht, const float* __restrict__ Whg,
                u16* __restrict__ comb, u16* __restrict__ wcat,
                u16* __restrict__ wht2)
{
  const int NC_COMB = (B_ * KC_) / 4;          // 6291456
  const int NC_WCAT = (4 * H_ * KC_) / 4;      // 1572864
  const int NC_WHT  = (2 * H_ * IN_) / 4;      // 262144
  const int TOTAL = NC_COMB + NC_WCAT + NC_WHT;
  const int stride = gridDim.x * blockDim.x;

  for (int idx = blockIdx.x * blockDim.x + threadIdx.x; idx < TOTAL; idx += stride) {
    const float* src;
    u16* dst;
    if (idx < NC_COMB) {
      int row = idx / 384, cq = idx % 384;
      src = (cq < 128) ? (x + (size_t)row * IN_ + cq * 4)
                       : (hprev + (size_t)row * H_ + (cq - 128) * 4);
      dst = comb + (size_t)idx * 4;
    } else if (idx < NC_COMB + NC_WCAT) {
      int j = idx - NC_COMB;
      int g = j / 393216;
      int rem = j % 393216;
      const float* W = (g == 0) ? Wi : (g == 1) ? Wf : (g == 2) ? Wo : Wg;
      src = W + (size_t)rem * 4;
      dst = wcat + (size_t)j * 4;
    } else {
      int j = idx - NC_COMB - NC_WCAT;
      int m = j / 131072;
      int rem = j % 131072;
      src = (m ? Whg : Wht) + (size_t)rem * 4;
      dst = wht2 + (size_t)j * 4;
    }
    float4 v = *(const float4*)src;
    uint32_t p0 = (uint32_t)f2bf(v.x) | ((uint32_t)f2bf(v.y) << 16);
    uint32_t p1 = (uint32_t)f2bf(v.z) | ((uint32_t)f2bf(v.w) << 16);
    *(uint2*)dst = make_uint2(p0, p1);
  }
}

// ---------- K1: gate GEMM + LSTM pointwise + partial attention logits ----------
// (proven R2 2-phase 128x128-eff structure, 218us / MfmaUtil 44% / 0 conflicts)
// Block tile: 128 rows x (4 gates x 32 h-cols), BK=64. 4 waves 2x2.
// Epilogue additionally computes partial_logit[bx][row] = sum over this
// block's 32 h-cols of h*Wa (shfl butterfly over lrow + LDS wn-combine).
__global__ __launch_bounds__(256, 2)
void k1_gates(const u16* __restrict__ comb, const u16* __restrict__ wcat,
              const float* __restrict__ bi, const float* __restrict__ bf_,
              const float* __restrict__ bo, const float* __restrict__ bg,
              const float* __restrict__ c_prev, const float* __restrict__ Wa,
              float* __restrict__ c_out, float* __restrict__ h_pre,
              float* __restrict__ partial_logit)
{
  __shared__ __attribute__((aligned(128))) char lds[32768];
  char* lds_a = lds;            // 128x64 bf16 = 16KB (content column-chunk-swizzled)
  char* lds_b = lds + 16384;    // 16KB

  const int tid = threadIdx.x;
  const int w = tid >> 6, lane = tid & 63;
  const int lrow = lane & 15, lkg = lane >> 4;
  const int wm = w >> 1, wn = w & 1;
  const int m0 = blockIdx.y * 128;
  const int n0 = blockIdx.x * 32;

  // staging: chunk j = w*256 + t*64 + lane; r=j>>3 row, q=j&7 16B-chunk-in-row
  const u16* agp[4]; const u16* bgp[4];
  char* alp[4]; char* blp[4];
#pragma unroll
  for (int t = 0; t < 4; ++t) {
    int j = w * 256 + t * 64 + lane;
    int r = j >> 3, q = j & 7;
    int qs = q ^ (r & 7);                                     // inverse-swizzled source
    agp[t] = comb + (size_t)(m0 + r) * KC_ + qs * 8;
    alp[t] = lds_a + (w * 256 + t * 64) * 16;
    int g = (r >> 4) & 3, n = ((r >> 6) << 4) + (r & 15);
    bgp[t] = wcat + ((size_t)(g * H_ + n0 + n)) * KC_ + qs * 8;
    blp[t] = lds_b + (w * 256 + t * 64) * 16;
  }

  f32x4 acc[4][4];
#pragma unroll
  for (int i = 0; i < 4; ++i)
#pragma unroll
    for (int j = 0; j < 4; ++j) acc[i][j] = (f32x4){0.f, 0.f, 0.f, 0.f};

  const int sw = (lrow & 7) << 4;   // XOR-swizzle for 128B-stride rows (G4)
  int aoff[4], boff[4];
#pragma unroll
  for (int fm = 0; fm < 4; ++fm) aoff[fm] = (wm * 64 + fm * 16 + lrow) * 128;
#pragma unroll
  for (int fc = 0; fc < 4; ++fc) boff[fc] = (wn * 64 + fc * 16 + lrow) * 128;

  for (int kt = 0; kt < KC_ / 64; ++kt) {
#pragma unroll
    for (int t = 0; t < 4; ++t) {
      async_copy16(alp[t], agp[t] + kt * 64);
      async_copy16(blp[t], bgp[t] + kt * 64);
    }
    __syncthreads();
#pragma unroll
    for (int ks = 0; ks < 2; ++ks) {
      const int koff = (ks * 64 + lkg * 16) ^ sw;
      s16x8 a[4], b[4];
#pragma unroll
      for (int fm = 0; fm < 4; ++fm) a[fm] = *(const s16x8*)(lds_a + aoff[fm] + koff);
#pragma unroll
      for (int fc = 0; fc < 4; ++fc) b[fc] = *(const s16x8*)(lds_b + boff[fc] + koff);
#pragma unroll
      for (int fm = 0; fm < 4; ++fm)
#pragma unroll
        for (int fc = 0; fc < 4; ++fc) mfma_bf16(acc[fm][fc], a[fm], b[fc]);
    }
    __syncthreads();
  }

  // epilogue: i,f,o,g -> c, h_pre; accumulate h*Wa partials
  const int h = n0 + wn * 16 + lrow;
  const float vbi = bi[h], vbf = bf_[h], vbo = bo[h], vbg = bg[h];
  const float wa_h = Wa[h];
  float slog[4][4];
#pragma unroll
  for (int fm = 0; fm < 4; ++fm) {
    const int row0 = m0 + wm * 64 + fm * 16 + lkg * 4;
#pragma unroll
    for (int r4 = 0; r4 < 4; ++r4) {
      const size_t off = (size_t)(row0 + r4) * H_ + h;
      float iv = fast_sigmoid(acc[fm][0][r4] + vbi);
      float fv = fast_sigmoid(acc[fm][1][r4] + vbf);
      float ov = fast_sigmoid(acc[fm][2][r4] + vbo);
      float gv = fast_tanh(acc[fm][3][r4] + vbg);
      float c = fv * c_prev[off] + iv * gv;
      c_out[off] = c;
      float hv = ov * fast_tanh(c);
      h_pre[off] = hv;
      slog[fm][r4] = hv * wa_h;
    }
  }
  // butterfly over the 16-lane lrow group: sum over this wave's 16 h-cols
#pragma unroll
  for (int fm = 0; fm < 4; ++fm)
#pragma unroll
    for (int r4 = 0; r4 < 4; ++r4) {
#pragma unroll
      for (int st = 1; st < 16; st <<= 1)
        slog[fm][r4] += __shfl_xor(slog[fm][r4], st);
    }
  // combine wn=0/1 halves via LDS (GEMM LDS is dead past last barrier)
  float* part = (float*)lds;     // part[wn][128]
  if (lrow == 0) {
#pragma unroll
    for (int fm = 0; fm < 4; ++fm)
#pragma unroll
      for (int r4 = 0; r4 < 4; ++r4)
        part[wn * 128 + wm * 64 + fm * 16 + lkg * 4 + r4] = slog[fm][r4];
  }
  __syncthreads();
  if (tid < 128)
    partial_logit[(size_t)blockIdx.x * B_ + m0 + tid] = part[tid] + part[128 + tid];
}

// ---------- K2: logits -> e = exp(logit+ba), per-block e-sums ----------
__global__ __launch_bounds__(256)
void k2_expsum(const float* __restrict__ partial_logit, const float* __restrict__ ba,
               float* __restrict__ e, float* __restrict__ psum)
{
  __shared__ float ws4[4];
  const int r = blockIdx.x * 256 + threadIdx.x;
  const int w = threadIdx.x >> 6, lane = threadIdx.x & 63;
  float s = 0.f;
#pragma unroll
  for (int p = 0; p < 32; ++p) s += partial_logit[(size_t)p * B_ + r];
  float ev = __expf(s + ba[0]);
  e[r] = ev;
  float t = ev;
#pragma unroll
  for (int off = 32; off; off >>= 1) t += __shfl_xor(t, off);
  if (lane == 0) ws4[w] = t;
  __syncthreads();
  if (threadIdx.x == 0) psum[blockIdx.x] = ws4[0] + ws4[1] + ws4[2] + ws4[3];
}

// ---------- K3: highway GEMM + attention scale + merge (128^2 2-phase) ----------
// Computes the softmax denominator itself from psum[64] (per-wave shuffle).
__global__ __launch_bounds__(256, 2)
void k3_highway(const u16* __restrict__ comb, const u16* __restrict__ wht2,
                const float* __restrict__ bht, const float* __restrict__ bhg,
                const float* __restrict__ e, const float* __restrict__ psum,
                float* __restrict__ h_out)   // holds h_pre (f32) on entry
{
  __shared__ __attribute__((aligned(128))) char lds[32768];
  char* lds_a = lds;
  char* lds_b = lds + 16384;

  const int tid = threadIdx.x;
  const int w = tid >> 6, lane = tid & 63;
  const int lrow = lane & 15, lkg = lane >> 4;
  const int wm = w >> 1, wn = w & 1;
  const int m0 = blockIdx.y * 128;
  const int h0 = blockIdx.x * 64;

  const u16* agp[4]; const u16* bgp[4];
  char* alp[4]; char* blp[4];
#pragma unroll
  for (int t = 0; t < 4; ++t) {
    int j = w * 256 + t * 64 + lane;
    int r = j >> 3, q = j & 7;
    int qs = q ^ (r & 7);
    agp[t] = comb + (size_t)(m0 + r) * KC_ + qs * 8;        // x part: cols 0..511
    alp[t] = lds_a + (w * 256 + t * 64) * 16;
    int mat = (r >> 4) & 1, n = ((r >> 5) << 4) + (r & 15);
    bgp[t] = wht2 + ((size_t)(mat * H_ + h0 + n)) * IN_ + qs * 8;
    blp[t] = lds_b + (w * 256 + t * 64) * 16;
  }

  f32x4 acc[4][4];
#pragma unroll
  for (int i = 0; i < 4; ++i)
#pragma unroll
    for (int j = 0; j < 4; ++j) acc[i][j] = (f32x4){0.f, 0.f, 0.f, 0.f};

  const int sw = (lrow & 7) << 4;
  int aoff[4], boff[4];
#pragma unroll
  for (int fm = 0; fm < 4; ++fm) aoff[fm] = (wm * 64 + fm * 16 + lrow) * 128;
#pragma unroll
  for (int fc = 0; fc < 4; ++fc) boff[fc] = (wn * 64 + fc * 16 + lrow) * 128;

  for (int kt = 0; kt < IN_ / 64; ++kt) {
#pragma unroll
    for (int t = 0; t < 4; ++t) {
      async_copy16(alp[t], agp[t] + kt * 64);
      async_copy16(blp[t], bgp[t] + kt * 64);
    }
    __syncthreads();
#pragma unroll
    for (int ks = 0; ks < 2; ++ks) {
      const int koff = (ks * 64 + lkg * 16) ^ sw;
      s16x8 a[4], b[4];
#pragma unroll
      for (int fm = 0; fm < 4; ++fm) a[fm] = *(const s16x8*)(lds_a + aoff[fm] + koff);
#pragma unroll
      for (int fc = 0; fc < 4; ++fc) b[fc] = *(const s16x8*)(lds_b + boff[fc] + koff);
#pragma unroll
      for (int fm = 0; fm < 4; ++fm)
#pragma unroll
        for (int fc = 0; fc < 4; ++fc) mfma_bf16(acc[fm][fc], a[fm], b[fc]);
    }
    __syncthreads();
  }

  // softmax denominator: every wave reduces psum[64] (L2-hot) via butterfly
  float sv = psum[lane];
#pragma unroll
  for (int off = 32; off; off >>= 1) sv += __shfl_xor(sv, off);
  const float invs = 1.f / sv;

  const int hA = h0 + wn * 32 + lrow;
  const float vbht0 = bht[hA], vbht1 = bht[hA + 16];
  const float vbhg0 = bhg[hA], vbhg1 = bhg[hA + 16];
#pragma unroll
  for (int fm = 0; fm < 4; ++fm) {
    const int row0 = m0 + wm * 64 + fm * 16 + lkg * 4;
#pragma unroll
    for (int r4 = 0; r4 < 4; ++r4) {
      const int row = row0 + r4;
      const float escale = e[row] * invs;
#pragma unroll
      for (int hc = 0; hc < 2; ++hc) {
        const int h = hA + hc * 16;
        const size_t off = (size_t)row * H_ + h;
        float tv = acc[fm][2 * hc][r4] + (hc ? vbht1 : vbht0);
        float gv = fast_sigmoid(acc[fm][2 * hc + 1][r4] + (hc ? vbhg1 : vbhg0));
        float ha = h_out[off] * escale;          // h_pre * attn
        h_out[off] = gv * tv + (1.f - gv) * ha;
      }
    }
  }
}

// ---------- launch ----------
extern "C" void kernel_launch(void* const* d_in, const int* in_sizes, int n_in,
                              void* d_out, int out_size, void* d_ws, size_t ws_size,
                              hipStream_t stream) {
  const float* x      = (const float*)d_in[0];
  const float* h_prev = (const float*)d_in[1];
  const float* c_prev = (const float*)d_in[2];
  const float* Wi  = (const float*)d_in[3];
  const float* bi  = (const float*)d_in[4];
  const float* Wf  = (const float*)d_in[5];
  const float* bf_ = (const float*)d_in[6];
  const float* Wo  = (const float*)d_in[7];
  const float* bo  = (const float*)d_in[8];
  const float* Wg  = (const float*)d_in[9];
  const float* bg  = (const float*)d_in[10];
  const float* Wa  = (const float*)d_in[11];
  const float* ba  = (const float*)d_in[12];
  const float* Wht = (const float*)d_in[13];
  const float* bht = (const float*)d_in[14];
  const float* Whg = (const float*)d_in[15];
  const float* bhg = (const float*)d_in[16];

  char* ws = (char*)d_ws;
  float* psum = (float*)(ws + 0);           // 64 floats
  float* e    = (float*)(ws + 256);         // 16384 floats -> 65792
  u16* comb = (u16*)(ws + 65792);           // 50331648 B
  u16* wcat = (u16*)(ws + 50397440);        // 12582912 B
  u16* wht2 = (u16*)(ws + 62980352);        // 2097152 B -> end 65077504
  float* partial_logit = (float*)(ws + 65077504);   // 32*16384*4 = 2097152 -> end 67174656

  float* h_out = (float*)d_out;                      // also h_pre scratch (f32)
  float* c_out = (float*)d_out + (size_t)B_ * H_;

  hipLaunchKernelGGL(k0_convert, dim3(2048), dim3(256), 0, stream,
                     x, h_prev, Wi, Wf, Wo, Wg, Wht, Whg, comb, wcat, wht2);
  hipLaunchKernelGGL(k1_gates, dim3(H_ / 32, B_ / 128), dim3(256), 0, stream,
                     comb, wcat, bi, bf_, bo, bg, c_prev, Wa, c_out, h_out, partial_logit);
  hipLaunchKernelGGL(k2_expsum, dim3(B_ / 256), dim3(256), 0, stream,
                     partial_logit, ba, e, psum);
  hipLaunchKernelGGL(k3_highway, dim3(H_ / 64, B_ / 128), dim3(256), 0, stream,
                     comb, wht2, bht, bhg, e, psum, h_out);
}